// Round 5
// baseline (74.410 us; speedup 1.0000x reference)
//
#include <hip/hip_runtime.h>

#ifndef __has_builtin
#define __has_builtin(x) 0
#endif

#if __has_builtin(__builtin_amdgcn_exp2f)
#define EXP2F(x) __builtin_amdgcn_exp2f(x)
#else
#define EXP2F(x) exp2f(x)
#endif
#if __has_builtin(__builtin_amdgcn_rcpf)
#define RCPF(x) __builtin_amdgcn_rcpf(x)
#else
#define RCPF(x) (1.0f / (x))
#endif

static constexpr int NB = 4, NQ = 512, NK = 512, DD = 512, HH = 128, DV = 512;
static constexpr float MASKV = -1e6f;
static constexpr float C2LOG2E = 2.885390081777926814f;  // 2*log2(e)

// ---------------------------------------------------------------------------
// K1: tiled GEMM for both projections, stacked rows (0..2047 q, 2048.. keys).
// 8-way K-split, tile 64x128, 256 thr, 4x8 micro-tile. Masked key tiles skip
// (their partials stay poison; epk of those rows is garbage but never read).
// ---------------------------------------------------------------------------
__global__ __launch_bounds__(256) void proj_gemm_kernel(
    const float* __restrict__ queries, const float* __restrict__ keys,
    const float* __restrict__ Wq, const float* __restrict__ Wk,
    const int* __restrict__ valid_lens, float* __restrict__ projpart) {
  const int mt = blockIdx.x >> 3;
  const int ks = blockIdx.x & 7;
  const int row0 = mt << 6;
  const int k0 = ks << 6;
  const float* inb;
  const float* W;
  if (row0 >= 2048) {
    const int local = row0 - 2048;
    if ((local & 511) >= valid_lens[local >> 9]) return;  // never consumed
    inb = keys + (size_t)local * DD;
    W = Wk;
  } else {
    inb = queries + (size_t)row0 * DD;
    W = Wq;
  }

  __shared__ float aS[64][65];
  __shared__ __align__(16) float bS[64][128];

  const int t = threadIdx.x;
#pragma unroll
  for (int f = 0; f < 4; ++f) {
    const int idx = t + (f << 8);
    const int r = idx >> 4, d0 = (idx & 15) << 2;
    const float4 v = *reinterpret_cast<const float4*>(inb + (size_t)r * DD + k0 + d0);
    aS[r][d0] = v.x; aS[r][d0 + 1] = v.y; aS[r][d0 + 2] = v.z; aS[r][d0 + 3] = v.w;
  }
#pragma unroll
  for (int f = 0; f < 8; ++f) {
    const int idx = t + (f << 8);
    const int dk = idx >> 5, c4 = (idx & 31) << 2;
    *reinterpret_cast<float4*>(&bS[dk][c4]) =
        *reinterpret_cast<const float4*>(W + (size_t)(k0 + dk) * HH + c4);
  }
  __syncthreads();

  const int tv = t & 15, tr = t >> 4;
  float acc[4][8];
#pragma unroll
  for (int i = 0; i < 4; ++i)
#pragma unroll
    for (int j = 0; j < 8; ++j) acc[i][j] = 0.f;

#pragma unroll 8
  for (int dk = 0; dk < 64; ++dk) {
    const float av[4] = {aS[(tr << 2) + 0][dk], aS[(tr << 2) + 1][dk],
                         aS[(tr << 2) + 2][dk], aS[(tr << 2) + 3][dk]};
    const float4 b0 = *reinterpret_cast<const float4*>(&bS[dk][tv << 2]);
    const float4 b1 = *reinterpret_cast<const float4*>(&bS[dk][64 + (tv << 2)]);
    const float bv[8] = {b0.x, b0.y, b0.z, b0.w, b1.x, b1.y, b1.z, b1.w};
#pragma unroll
    for (int i = 0; i < 4; ++i)
#pragma unroll
      for (int j = 0; j < 8; ++j) acc[i][j] = fmaf(av[i], bv[j], acc[i][j]);
  }

  float* pb = projpart + ((size_t)ks << 19) + (size_t)row0 * HH;
#pragma unroll
  for (int i = 0; i < 4; ++i) {
    float* rowp = pb + (size_t)((tr << 2) + i) * HH;
    *reinterpret_cast<float4*>(rowp + (tv << 2)) =
        make_float4(acc[i][0], acc[i][1], acc[i][2], acc[i][3]);
    *reinterpret_cast<float4*>(rowp + 64 + (tv << 2)) =
        make_float4(acc[i][4], acc[i][5], acc[i][6], acc[i][7]);
  }
}

// ---------------------------------------------------------------------------
// K2: epk[row][h] = exp2( C * sum_{ks<8} projpart[ks][row][h] )
// ---------------------------------------------------------------------------
__global__ __launch_bounds__(256) void proj_reduce_kernel(
    const float* __restrict__ projpart, float* __restrict__ epk) {
  const int i = blockIdx.x * 256 + threadIdx.x;
  const float4* p = reinterpret_cast<const float4*>(projpart);
  float4 s = p[i];
#pragma unroll
  for (int j = 1; j < 8; ++j) {
    const float4 v = p[i + j * 131072];
    s.x += v.x; s.y += v.y; s.z += v.z; s.w += v.w;
  }
  float4 r;
  r.x = EXP2F(s.x * C2LOG2E);
  r.y = EXP2F(s.y * C2LOG2E);
  r.z = EXP2F(s.z * C2LOG2E);
  r.w = EXP2F(s.w * C2LOG2E);
  reinterpret_cast<float4*>(epk)[i] = r;
}

// ---------------------------------------------------------------------------
// K3 (fused): scores + masked softmax + PV, writing d_out directly.
// Block = (b, 4 q-rows), 512 threads, 512 blocks (2/CU, batch pairs {0,2},
// {1,3} per CU — round-3's proven shape).
//  A: thread t = key t: s_q = -2*sum_h w_h/(1+eq*ek)  (fma+rcp+fma per elem)
//  B: waves 0..3 softmax rows 0..3 (shuffle reduce over 512 keys)
//  C: wave w -> (q=w&3, v-half=w>>2); lane owns float4 of v; P broadcast
//     from LDS, V float4-coalesced, O accumulated in regs -> d_out.
// ---------------------------------------------------------------------------
__global__ __launch_bounds__(512) void fused_attn_kernel(
    const float* __restrict__ eq, const float* __restrict__ ek,
    const float* __restrict__ Wv, const int* __restrict__ valid_lens,
    const float* __restrict__ values, float* __restrict__ out) {
  const int b = blockIdx.x >> 7;
  const int q0 = (blockIdx.x & 127) << 2;
  const int t = threadIdx.x;

  __shared__ __align__(16) float qs[4][HH];
  __shared__ __align__(16) float wv[HH];
  __shared__ __align__(16) float sc[4][NK];

  qs[t >> 7][t & 127] = eq[((size_t)(b * NQ + q0 + (t >> 7))) * HH + (t & 127)];
  if (t < HH) wv[t] = Wv[t];
  __syncthreads();

  const int vl = valid_lens[b];
  float s0 = 0.f, s1 = 0.f, s2 = 0.f, s3 = 0.f;

  if (t < vl) {
    const float* ekrow = ek + ((size_t)(b * NK + t)) * HH;
#pragma unroll 4
    for (int hs = 0; hs < HH; hs += 4) {
      const float4 k4 = *reinterpret_cast<const float4*>(ekrow + hs);
      const float4 w4 = *reinterpret_cast<const float4*>(&wv[hs]);
      const float4 qa = *reinterpret_cast<const float4*>(&qs[0][hs]);
      const float4 qb = *reinterpret_cast<const float4*>(&qs[1][hs]);
      const float4 qc = *reinterpret_cast<const float4*>(&qs[2][hs]);
      const float4 qd = *reinterpret_cast<const float4*>(&qs[3][hs]);
      float d, r;
      d = fmaf(qa.x, k4.x, 1.f); r = RCPF(d); s0 = fmaf(w4.x, r, s0);
      d = fmaf(qa.y, k4.y, 1.f); r = RCPF(d); s0 = fmaf(w4.y, r, s0);
      d = fmaf(qa.z, k4.z, 1.f); r = RCPF(d); s0 = fmaf(w4.z, r, s0);
      d = fmaf(qa.w, k4.w, 1.f); r = RCPF(d); s0 = fmaf(w4.w, r, s0);
      d = fmaf(qb.x, k4.x, 1.f); r = RCPF(d); s1 = fmaf(w4.x, r, s1);
      d = fmaf(qb.y, k4.y, 1.f); r = RCPF(d); s1 = fmaf(w4.y, r, s1);
      d = fmaf(qb.z, k4.z, 1.f); r = RCPF(d); s1 = fmaf(w4.z, r, s1);
      d = fmaf(qb.w, k4.w, 1.f); r = RCPF(d); s1 = fmaf(w4.w, r, s1);
      d = fmaf(qc.x, k4.x, 1.f); r = RCPF(d); s2 = fmaf(w4.x, r, s2);
      d = fmaf(qc.y, k4.y, 1.f); r = RCPF(d); s2 = fmaf(w4.y, r, s2);
      d = fmaf(qc.z, k4.z, 1.f); r = RCPF(d); s2 = fmaf(w4.z, r, s2);
      d = fmaf(qc.w, k4.w, 1.f); r = RCPF(d); s2 = fmaf(w4.w, r, s2);
      d = fmaf(qd.x, k4.x, 1.f); r = RCPF(d); s3 = fmaf(w4.x, r, s3);
      d = fmaf(qd.y, k4.y, 1.f); r = RCPF(d); s3 = fmaf(w4.y, r, s3);
      d = fmaf(qd.z, k4.z, 1.f); r = RCPF(d); s3 = fmaf(w4.z, r, s3);
      d = fmaf(qd.w, k4.w, 1.f); r = RCPF(d); s3 = fmaf(w4.w, r, s3);
    }
  }
  const bool act = (t < vl);
  sc[0][t] = act ? (-2.f * s0) : MASKV;
  sc[1][t] = act ? (-2.f * s1) : MASKV;
  sc[2][t] = act ? (-2.f * s2) : MASKV;
  sc[3][t] = act ? (-2.f * s3) : MASKV;
  __syncthreads();

  // B: softmax, wave w (<4) handles q-row w over all 512 keys
  const int w = t >> 6, l = t & 63;
  if (w < 4) {
    float v[8];
#pragma unroll
    for (int j = 0; j < 8; ++j) v[j] = sc[w][l + (j << 6)];
    float m = v[0];
#pragma unroll
    for (int j = 1; j < 8; ++j) m = fmaxf(m, v[j]);
#pragma unroll
    for (int off = 32; off > 0; off >>= 1) m = fmaxf(m, __shfl_xor(m, off, 64));
    float p[8], sum = 0.f;
#pragma unroll
    for (int j = 0; j < 8; ++j) {
      p[j] = __expf(v[j] - m);  // masked: underflows to exactly 0
      sum += p[j];
    }
#pragma unroll
    for (int off = 32; off > 0; off >>= 1) sum += __shfl_xor(sum, off, 64);
    const float inv = RCPF(sum);
#pragma unroll
    for (int j = 0; j < 8; ++j) sc[w][l + (j << 6)] = p[j] * inv;
  }
  __syncthreads();

  // C: PV. wave w -> q = w&3, v-half = w>>2; lane l owns v = v0 + 4l.
  const int q = w & 3;
  const int vcol = ((w >> 2) << 8) + (l << 2);
  const float* vb = values + ((size_t)b * NK) * DV + vcol;
  float4 acc = make_float4(0.f, 0.f, 0.f, 0.f);
  const int vr = (vl + 3) & ~3;
#pragma unroll 2
  for (int k = 0; k < vr; k += 4) {
    const float4 p4 = *reinterpret_cast<const float4*>(&sc[q][k]);  // broadcast
    const float4 va = *reinterpret_cast<const float4*>(vb + (size_t)(k + 0) * DV);
    const float4 vb2 = *reinterpret_cast<const float4*>(vb + (size_t)(k + 1) * DV);
    const float4 vc = *reinterpret_cast<const float4*>(vb + (size_t)(k + 2) * DV);
    const float4 vd = *reinterpret_cast<const float4*>(vb + (size_t)(k + 3) * DV);
    acc.x = fmaf(p4.x, va.x, acc.x); acc.y = fmaf(p4.x, va.y, acc.y);
    acc.z = fmaf(p4.x, va.z, acc.z); acc.w = fmaf(p4.x, va.w, acc.w);
    acc.x = fmaf(p4.y, vb2.x, acc.x); acc.y = fmaf(p4.y, vb2.y, acc.y);
    acc.z = fmaf(p4.y, vb2.z, acc.z); acc.w = fmaf(p4.y, vb2.w, acc.w);
    acc.x = fmaf(p4.z, vc.x, acc.x); acc.y = fmaf(p4.z, vc.y, acc.y);
    acc.z = fmaf(p4.z, vc.z, acc.z); acc.w = fmaf(p4.z, vc.w, acc.w);
    acc.x = fmaf(p4.w, vd.x, acc.x); acc.y = fmaf(p4.w, vd.y, acc.y);
    acc.z = fmaf(p4.w, vd.z, acc.z); acc.w = fmaf(p4.w, vd.w, acc.w);
  }
  *reinterpret_cast<float4*>(out + ((size_t)(b * NQ + q0 + q)) * DV + vcol) = acc;
}

extern "C" void kernel_launch(void* const* d_in, const int* in_sizes, int n_in,
                              void* d_out, int out_size, void* d_ws, size_t ws_size,
                              hipStream_t stream) {
  (void)in_sizes; (void)n_in; (void)out_size; (void)ws_size;
  const float* queries = (const float*)d_in[0];
  const float* keys    = (const float*)d_in[1];
  const float* values  = (const float*)d_in[2];
  const float* Wq      = (const float*)d_in[3];
  const float* Wk      = (const float*)d_in[4];
  const float* Wv      = (const float*)d_in[5];
  const int*   vlens   = (const int*)d_in[6];
  float* out = (float*)d_out;
  float* ws = (float*)d_ws;

  // ws floats: epk 524288 | projpart 4194304
  float* epk      = ws;                 // eq rows 0..2047, ek rows 2048..4095
  float* eq       = epk;
  float* ek       = epk + 262144;
  float* projpart = ws + 524288;

  proj_gemm_kernel<<<512, 256, 0, stream>>>(queries, keys, Wq, Wk, vlens, projpart);
  proj_reduce_kernel<<<512, 256, 0, stream>>>(projpart, epk);
  fused_attn_kernel<<<512, 512, 0, stream>>>(eq, ek, Wv, vlens, values, out);
}

// Round 6
// 60.606 us; speedup vs baseline: 1.2278x; 1.2278x over previous
//
#include <hip/hip_runtime.h>

#ifndef __has_builtin
#define __has_builtin(x) 0
#endif

#if __has_builtin(__builtin_amdgcn_exp2f)
#define EXP2F(x) __builtin_amdgcn_exp2f(x)
#else
#define EXP2F(x) exp2f(x)
#endif
#if __has_builtin(__builtin_amdgcn_rcpf)
#define RCPF(x) __builtin_amdgcn_rcpf(x)
#else
#define RCPF(x) (1.0f / (x))
#endif

static constexpr int NB = 4, NQ = 512, NK = 512, DD = 512, HH = 128, DV = 512;
static constexpr float MASKV = -1e6f;
static constexpr float C2LOG2E = 2.885390081777926814f;  // 2*log2(e)

// ---------------------------------------------------------------------------
// K1: tiled GEMM for both projections, stacked rows (0..2047 q, 2048.. keys).
// 8-way K-split, tile 64x128, 256 thr, 4x8 micro-tile. Masked key tiles skip
// (their partials stay poison; never read downstream).
// ---------------------------------------------------------------------------
__global__ __launch_bounds__(256) void proj_gemm_kernel(
    const float* __restrict__ queries, const float* __restrict__ keys,
    const float* __restrict__ Wq, const float* __restrict__ Wk,
    const int* __restrict__ valid_lens, float* __restrict__ projpart) {
  const int mt = blockIdx.x >> 3;
  const int ks = blockIdx.x & 7;
  const int row0 = mt << 6;
  const int k0 = ks << 6;
  const float* inb;
  const float* W;
  if (row0 >= 2048) {
    const int local = row0 - 2048;
    if ((local & 511) >= valid_lens[local >> 9]) return;  // never consumed
    inb = keys + (size_t)local * DD;
    W = Wk;
  } else {
    inb = queries + (size_t)row0 * DD;
    W = Wq;
  }

  __shared__ float aS[64][65];
  __shared__ __align__(16) float bS[64][128];

  const int t = threadIdx.x;
#pragma unroll
  for (int f = 0; f < 4; ++f) {
    const int idx = t + (f << 8);
    const int r = idx >> 4, d0 = (idx & 15) << 2;
    const float4 v = *reinterpret_cast<const float4*>(inb + (size_t)r * DD + k0 + d0);
    aS[r][d0] = v.x; aS[r][d0 + 1] = v.y; aS[r][d0 + 2] = v.z; aS[r][d0 + 3] = v.w;
  }
#pragma unroll
  for (int f = 0; f < 8; ++f) {
    const int idx = t + (f << 8);
    const int dk = idx >> 5, c4 = (idx & 31) << 2;
    *reinterpret_cast<float4*>(&bS[dk][c4]) =
        *reinterpret_cast<const float4*>(W + (size_t)(k0 + dk) * HH + c4);
  }
  __syncthreads();

  const int tv = t & 15, tr = t >> 4;
  float acc[4][8];
#pragma unroll
  for (int i = 0; i < 4; ++i)
#pragma unroll
    for (int j = 0; j < 8; ++j) acc[i][j] = 0.f;

#pragma unroll 8
  for (int dk = 0; dk < 64; ++dk) {
    const float av[4] = {aS[(tr << 2) + 0][dk], aS[(tr << 2) + 1][dk],
                         aS[(tr << 2) + 2][dk], aS[(tr << 2) + 3][dk]};
    const float4 b0 = *reinterpret_cast<const float4*>(&bS[dk][tv << 2]);
    const float4 b1 = *reinterpret_cast<const float4*>(&bS[dk][64 + (tv << 2)]);
    const float bv[8] = {b0.x, b0.y, b0.z, b0.w, b1.x, b1.y, b1.z, b1.w};
#pragma unroll
    for (int i = 0; i < 4; ++i)
#pragma unroll
      for (int j = 0; j < 8; ++j) acc[i][j] = fmaf(av[i], bv[j], acc[i][j]);
  }

  float* pb = projpart + ((size_t)ks << 19) + (size_t)row0 * HH;
#pragma unroll
  for (int i = 0; i < 4; ++i) {
    float* rowp = pb + (size_t)((tr << 2) + i) * HH;
    *reinterpret_cast<float4*>(rowp + (tv << 2)) =
        make_float4(acc[i][0], acc[i][1], acc[i][2], acc[i][3]);
    *reinterpret_cast<float4*>(rowp + 64 + (tv << 2)) =
        make_float4(acc[i][4], acc[i][5], acc[i][6], acc[i][7]);
  }
}

// ---------------------------------------------------------------------------
// K2: reduce the 8 K-split partials, exp2-transform, and store:
//   blocks 0..255  -> eq[row][h]   (flat, rows 0..2047 = queries)
//   blocks 256..511 -> ekT[b][h][k] (transposed scatter, keys; masked rows skip)
// ---------------------------------------------------------------------------
__global__ __launch_bounds__(256) void proj_reduce_kernel(
    const float* __restrict__ projpart, const int* __restrict__ valid_lens,
    float* __restrict__ eq, float* __restrict__ ekT) {
  const int bid = blockIdx.x;
  const float4* p = reinterpret_cast<const float4*>(projpart);
  if (bid < 256) {
    const int i = bid * 256 + threadIdx.x;  // float4 idx into q-half (65536)
    float4 s = p[i];
#pragma unroll
    for (int j = 1; j < 8; ++j) {
      const float4 v = p[i + j * 131072];
      s.x += v.x; s.y += v.y; s.z += v.z; s.w += v.w;
    }
    float4 r;
    r.x = EXP2F(s.x * C2LOG2E);
    r.y = EXP2F(s.y * C2LOG2E);
    r.z = EXP2F(s.z * C2LOG2E);
    r.w = EXP2F(s.w * C2LOG2E);
    reinterpret_cast<float4*>(eq)[i] = r;
  } else {
    const int j = (bid - 256) * 256 + threadIdx.x;  // float4 idx in k-half
    const int rl = j >> 5;            // local key row 0..2047
    const int b = rl >> 9, k = rl & 511;
    if (k >= valid_lens[b]) return;   // masked: never read downstream
    const int h0 = (j & 31) << 2;
    float4 s = p[65536 + j];
#pragma unroll
    for (int jj = 1; jj < 8; ++jj) {
      const float4 v = p[65536 + j + jj * 131072];
      s.x += v.x; s.y += v.y; s.z += v.z; s.w += v.w;
    }
    float* dst = ekT + ((size_t)b << 16) + k;
    dst[(size_t)(h0 + 0) << 9] = EXP2F(s.x * C2LOG2E);
    dst[(size_t)(h0 + 1) << 9] = EXP2F(s.y * C2LOG2E);
    dst[(size_t)(h0 + 2) << 9] = EXP2F(s.z * C2LOG2E);
    dst[(size_t)(h0 + 3) << 9] = EXP2F(s.w * C2LOG2E);
  }
}

// ---------------------------------------------------------------------------
// K3: scores + masked softmax. Block = (b, 4 q-rows), 512 thr, 512 blocks.
// Phase A: thread t = key t; ekT[h][t] reads are COALESCED across lanes
// (256 contiguous bytes per wave-instr). score = -2*sum_h w_h/(1+eq*ek).
// Phase B: waves 0..3 softmax rows 0..3. Writes attnT[b][k][q] (k-major).
// ---------------------------------------------------------------------------
__global__ __launch_bounds__(512) void scores_softmax_kernel(
    const float* __restrict__ eq, const float* __restrict__ ekT,
    const float* __restrict__ Wv, const int* __restrict__ valid_lens,
    float* __restrict__ attnT) {
  const int b = blockIdx.x >> 7;
  const int q0 = (blockIdx.x & 127) << 2;
  const int t = threadIdx.x;

  __shared__ __align__(16) float qs[4][HH];
  __shared__ __align__(16) float wv[HH];
  __shared__ __align__(16) float sc[4][NK];

  qs[t >> 7][t & 127] = eq[((size_t)(b * NQ + q0 + (t >> 7))) * HH + (t & 127)];
  if (t < HH) wv[t] = Wv[t];
  __syncthreads();

  const int vl = valid_lens[b];
  float s0 = 0.f, s1 = 0.f, s2 = 0.f, s3 = 0.f;

  if (t < vl) {
    const float* ekb = ekT + ((size_t)b << 16) + t;  // column t of [128][512]
#pragma unroll 4
    for (int h = 0; h < HH; h += 4) {
      const float e0 = ekb[(size_t)(h + 0) << 9];
      const float e1 = ekb[(size_t)(h + 1) << 9];
      const float e2 = ekb[(size_t)(h + 2) << 9];
      const float e3 = ekb[(size_t)(h + 3) << 9];
      const float4 w4 = *reinterpret_cast<const float4*>(&wv[h]);
      const float4 qa = *reinterpret_cast<const float4*>(&qs[0][h]);
      const float4 qb = *reinterpret_cast<const float4*>(&qs[1][h]);
      const float4 qc = *reinterpret_cast<const float4*>(&qs[2][h]);
      const float4 qd = *reinterpret_cast<const float4*>(&qs[3][h]);
      float d, r;
      d = fmaf(qa.x, e0, 1.f); r = RCPF(d); s0 = fmaf(w4.x, r, s0);
      d = fmaf(qa.y, e1, 1.f); r = RCPF(d); s0 = fmaf(w4.y, r, s0);
      d = fmaf(qa.z, e2, 1.f); r = RCPF(d); s0 = fmaf(w4.z, r, s0);
      d = fmaf(qa.w, e3, 1.f); r = RCPF(d); s0 = fmaf(w4.w, r, s0);
      d = fmaf(qb.x, e0, 1.f); r = RCPF(d); s1 = fmaf(w4.x, r, s1);
      d = fmaf(qb.y, e1, 1.f); r = RCPF(d); s1 = fmaf(w4.y, r, s1);
      d = fmaf(qb.z, e2, 1.f); r = RCPF(d); s1 = fmaf(w4.z, r, s1);
      d = fmaf(qb.w, e3, 1.f); r = RCPF(d); s1 = fmaf(w4.w, r, s1);
      d = fmaf(qc.x, e0, 1.f); r = RCPF(d); s2 = fmaf(w4.x, r, s2);
      d = fmaf(qc.y, e1, 1.f); r = RCPF(d); s2 = fmaf(w4.y, r, s2);
      d = fmaf(qc.z, e2, 1.f); r = RCPF(d); s2 = fmaf(w4.z, r, s2);
      d = fmaf(qc.w, e3, 1.f); r = RCPF(d); s2 = fmaf(w4.w, r, s2);
      d = fmaf(qd.x, e0, 1.f); r = RCPF(d); s3 = fmaf(w4.x, r, s3);
      d = fmaf(qd.y, e1, 1.f); r = RCPF(d); s3 = fmaf(w4.y, r, s3);
      d = fmaf(qd.z, e2, 1.f); r = RCPF(d); s3 = fmaf(w4.z, r, s3);
      d = fmaf(qd.w, e3, 1.f); r = RCPF(d); s3 = fmaf(w4.w, r, s3);
    }
  }
  const bool act = (t < vl);
  sc[0][t] = act ? (-2.f * s0) : MASKV;
  sc[1][t] = act ? (-2.f * s1) : MASKV;
  sc[2][t] = act ? (-2.f * s2) : MASKV;
  sc[3][t] = act ? (-2.f * s3) : MASKV;
  __syncthreads();

  // softmax: wave w (<4) handles q-row w over all 512 keys
  const int w = t >> 6, l = t & 63;
  if (w < 4) {
    float v[8];
#pragma unroll
    for (int j = 0; j < 8; ++j) v[j] = sc[w][l + (j << 6)];
    float m = v[0];
#pragma unroll
    for (int j = 1; j < 8; ++j) m = fmaxf(m, v[j]);
#pragma unroll
    for (int off = 32; off > 0; off >>= 1) m = fmaxf(m, __shfl_xor(m, off, 64));
    float p[8], sum = 0.f;
#pragma unroll
    for (int j = 0; j < 8; ++j) {
      p[j] = __expf(v[j] - m);  // masked: underflows to exactly 0
      sum += p[j];
    }
#pragma unroll
    for (int off = 32; off > 0; off >>= 1) sum += __shfl_xor(sum, off, 64);
    const float inv = RCPF(sum);
#pragma unroll
    for (int j = 0; j < 8; ++j) sc[w][l + (j << 6)] = p[j] * inv;
  }
  __syncthreads();

  const float4 o = make_float4(sc[0][t], sc[1][t], sc[2][t], sc[3][t]);
  *reinterpret_cast<float4*>(attnT + ((size_t)(b * NK + t)) * NQ + q0) = o;
}

// ---------------------------------------------------------------------------
// K4: partial[ks][b][q][v] = sum_{k in split} attnT[b][k][q]*values[b][k][v]
// 128x128 C-tile, 512 threads, 4x8 micro-tile, BK=16, 4-way K-split.
// (round-3 proven version)
// ---------------------------------------------------------------------------
__global__ __launch_bounds__(512) void pv_gemm_kernel(
    const float* __restrict__ attnT, const float* __restrict__ values,
    const int* __restrict__ valid_lens, float* __restrict__ partial) {
  const int bid = blockIdx.x;
  const int ks = bid & 3;
  const int tile = (bid >> 2) & 15;
  const int b = bid >> 6;
  const int q0 = (tile >> 2) << 7;
  const int v0 = (tile & 3) << 7;
  const int kbase = ks << 7;

  __shared__ __align__(16) float aT[16][128];
  __shared__ __align__(16) float bS[16][128];

  const int tid = threadIdx.x;
  const int tv = tid & 15, tq = tid >> 4;

  float acc[4][8];
#pragma unroll
  for (int i = 0; i < 4; ++i)
#pragma unroll
    for (int j = 0; j < 8; ++j) acc[i][j] = 0.f;

  if (kbase < valid_lens[b]) {
    const int sdk = tid >> 5, sc4 = (tid & 31) << 2;
    for (int kt = 0; kt < 8; ++kt) {
      const int k0 = kbase + (kt << 4);
      *reinterpret_cast<float4*>(&aT[sdk][sc4]) =
          *reinterpret_cast<const float4*>(attnT + ((size_t)(b * NK + k0 + sdk)) * NQ + q0 + sc4);
      *reinterpret_cast<float4*>(&bS[sdk][sc4]) =
          *reinterpret_cast<const float4*>(values + ((size_t)(b * NK + k0 + sdk)) * DV + v0 + sc4);
      __syncthreads();
#pragma unroll
      for (int dk = 0; dk < 16; ++dk) {
        const float4 a4 = *reinterpret_cast<const float4*>(&aT[dk][tq << 2]);
        const float4 b0 = *reinterpret_cast<const float4*>(&bS[dk][tv << 2]);
        const float4 b1 = *reinterpret_cast<const float4*>(&bS[dk][64 + (tv << 2)]);
        const float av[4] = {a4.x, a4.y, a4.z, a4.w};
        const float bv[8] = {b0.x, b0.y, b0.z, b0.w, b1.x, b1.y, b1.z, b1.w};
#pragma unroll
        for (int i = 0; i < 4; ++i)
#pragma unroll
          for (int j = 0; j < 8; ++j) acc[i][j] = fmaf(av[i], bv[j], acc[i][j]);
      }
      __syncthreads();
    }
  }

  float* pbase = partial + ((size_t)(ks * NB + b)) * NQ * DV;
#pragma unroll
  for (int i = 0; i < 4; ++i) {
    float* row = pbase + ((size_t)(q0 + (tq << 2) + i)) * DV + v0;
    *reinterpret_cast<float4*>(row + (tv << 2)) =
        make_float4(acc[i][0], acc[i][1], acc[i][2], acc[i][3]);
    *reinterpret_cast<float4*>(row + 64 + (tv << 2)) =
        make_float4(acc[i][4], acc[i][5], acc[i][6], acc[i][7]);
  }
}

// ---------------------------------------------------------------------------
// K5: out = sum of the 4 K-split partials
// ---------------------------------------------------------------------------
__global__ __launch_bounds__(256) void reduce4_kernel(
    const float* __restrict__ partial, float* __restrict__ out) {
  const int i = blockIdx.x * 256 + threadIdx.x;
  const float4* p = reinterpret_cast<const float4*>(partial);
  const float4 a = p[i];
  const float4 b = p[i + 262144];
  const float4 c = p[i + 524288];
  const float4 d = p[i + 786432];
  float4 r;
  r.x = a.x + b.x + c.x + d.x;
  r.y = a.y + b.y + c.y + d.y;
  r.z = a.z + b.z + c.z + d.z;
  r.w = a.w + b.w + c.w + d.w;
  reinterpret_cast<float4*>(out)[i] = r;
}

extern "C" void kernel_launch(void* const* d_in, const int* in_sizes, int n_in,
                              void* d_out, int out_size, void* d_ws, size_t ws_size,
                              hipStream_t stream) {
  (void)in_sizes; (void)n_in; (void)out_size; (void)ws_size;
  const float* queries = (const float*)d_in[0];
  const float* keys    = (const float*)d_in[1];
  const float* values  = (const float*)d_in[2];
  const float* Wq      = (const float*)d_in[3];
  const float* Wk      = (const float*)d_in[4];
  const float* Wv      = (const float*)d_in[5];
  const int*   vlens   = (const int*)d_in[6];
  float* out = (float*)d_out;
  float* ws = (float*)d_ws;

  // ws floats: eq 262144 | ekT 262144 | attnT 1048576 | pvpart 4194304 | projpart 4194304
  float* eq       = ws;
  float* ekT      = ws + 262144;
  float* attnT    = ws + 524288;
  float* pvpart   = ws + 1572864;
  float* projpart = ws + 5767168;

  proj_gemm_kernel<<<512, 256, 0, stream>>>(queries, keys, Wq, Wk, vlens, projpart);
  proj_reduce_kernel<<<512, 256, 0, stream>>>(projpart, vlens, eq, ekT);
  scores_softmax_kernel<<<512, 512, 0, stream>>>(eq, ekT, Wv, vlens, attnT);
  pv_gemm_kernel<<<256, 512, 0, stream>>>(attnT, values, vlens, pvpart);
  reduce4_kernel<<<1024, 256, 0, stream>>>(pvpart, out);
}

// Round 7
// 53.941 us; speedup vs baseline: 1.3795x; 1.1235x over previous
//
#include <hip/hip_runtime.h>

#ifndef __has_builtin
#define __has_builtin(x) 0
#endif

#if __has_builtin(__builtin_amdgcn_exp2f)
#define EXP2F(x) __builtin_amdgcn_exp2f(x)
#else
#define EXP2F(x) exp2f(x)
#endif
#if __has_builtin(__builtin_amdgcn_rcpf)
#define RCPF(x) __builtin_amdgcn_rcpf(x)
#else
#define RCPF(x) (1.0f / (x))
#endif

static constexpr int NB = 4, NQ = 512, NK = 512, DD = 512, HH = 128, DV = 512;
static constexpr float MASKV = -1e6f;
static constexpr float C2LOG2E = 2.885390081777926814f;  // 2*log2(e)

typedef __attribute__((ext_vector_type(8))) short bf16x8;
typedef __attribute__((ext_vector_type(4))) float f32x4;

__device__ __forceinline__ unsigned short f2bf(float x) {  // RNE f32->bf16
  unsigned int u = __float_as_uint(x);
  u += 0x7FFFu + ((u >> 16) & 1u);
  return (unsigned short)(u >> 16);
}

// ---------------------------------------------------------------------------
// K1: tiled GEMM for both projections, stacked rows (0..2047 q, 2048.. keys).
// 8-way K-split, tile 64x128, 256 thr, 4x8 micro-tile. Masked key tiles skip.
// ---------------------------------------------------------------------------
__global__ __launch_bounds__(256) void proj_gemm_kernel(
    const float* __restrict__ queries, const float* __restrict__ keys,
    const float* __restrict__ Wq, const float* __restrict__ Wk,
    const int* __restrict__ valid_lens, float* __restrict__ projpart) {
  const int mt = blockIdx.x >> 3;
  const int ks = blockIdx.x & 7;
  const int row0 = mt << 6;
  const int k0 = ks << 6;
  const float* inb;
  const float* W;
  if (row0 >= 2048) {
    const int local = row0 - 2048;
    if ((local & 511) >= valid_lens[local >> 9]) return;  // never consumed
    inb = keys + (size_t)local * DD;
    W = Wk;
  } else {
    inb = queries + (size_t)row0 * DD;
    W = Wq;
  }

  __shared__ float aS[64][65];
  __shared__ __align__(16) float bS[64][128];

  const int t = threadIdx.x;
#pragma unroll
  for (int f = 0; f < 4; ++f) {
    const int idx = t + (f << 8);
    const int r = idx >> 4, d0 = (idx & 15) << 2;
    const float4 v = *reinterpret_cast<const float4*>(inb + (size_t)r * DD + k0 + d0);
    aS[r][d0] = v.x; aS[r][d0 + 1] = v.y; aS[r][d0 + 2] = v.z; aS[r][d0 + 3] = v.w;
  }
#pragma unroll
  for (int f = 0; f < 8; ++f) {
    const int idx = t + (f << 8);
    const int dk = idx >> 5, c4 = (idx & 31) << 2;
    *reinterpret_cast<float4*>(&bS[dk][c4]) =
        *reinterpret_cast<const float4*>(W + (size_t)(k0 + dk) * HH + c4);
  }
  __syncthreads();

  const int tv = t & 15, tr = t >> 4;
  float acc[4][8];
#pragma unroll
  for (int i = 0; i < 4; ++i)
#pragma unroll
    for (int j = 0; j < 8; ++j) acc[i][j] = 0.f;

#pragma unroll 8
  for (int dk = 0; dk < 64; ++dk) {
    const float av[4] = {aS[(tr << 2) + 0][dk], aS[(tr << 2) + 1][dk],
                         aS[(tr << 2) + 2][dk], aS[(tr << 2) + 3][dk]};
    const float4 b0 = *reinterpret_cast<const float4*>(&bS[dk][tv << 2]);
    const float4 b1 = *reinterpret_cast<const float4*>(&bS[dk][64 + (tv << 2)]);
    const float bv[8] = {b0.x, b0.y, b0.z, b0.w, b1.x, b1.y, b1.z, b1.w};
#pragma unroll
    for (int i = 0; i < 4; ++i)
#pragma unroll
      for (int j = 0; j < 8; ++j) acc[i][j] = fmaf(av[i], bv[j], acc[i][j]);
  }

  float* pb = projpart + ((size_t)ks << 19) + (size_t)row0 * HH;
#pragma unroll
  for (int i = 0; i < 4; ++i) {
    float* rowp = pb + (size_t)((tr << 2) + i) * HH;
    *reinterpret_cast<float4*>(rowp + (tv << 2)) =
        make_float4(acc[i][0], acc[i][1], acc[i][2], acc[i][3]);
    *reinterpret_cast<float4*>(rowp + 64 + (tv << 2)) =
        make_float4(acc[i][4], acc[i][5], acc[i][6], acc[i][7]);
  }
}

// ---------------------------------------------------------------------------
// K2: reduce the 8 K-split partials, exp2-transform, and store:
//   blocks 0..255   -> eq[row][h]        (flat)
//   blocks 256..511 -> ekT4[b][h/4][k][4] (float4-packed transpose; masked skip)
// ---------------------------------------------------------------------------
__global__ __launch_bounds__(256) void proj_reduce_kernel(
    const float* __restrict__ projpart, const int* __restrict__ valid_lens,
    float* __restrict__ eq, float* __restrict__ ekT4) {
  const int bid = blockIdx.x;
  const float4* p = reinterpret_cast<const float4*>(projpart);
  if (bid < 256) {
    const int i = bid * 256 + threadIdx.x;  // float4 idx into q-half (65536)
    float4 s = p[i];
#pragma unroll
    for (int j = 1; j < 8; ++j) {
      const float4 v = p[i + j * 131072];
      s.x += v.x; s.y += v.y; s.z += v.z; s.w += v.w;
    }
    float4 r;
    r.x = EXP2F(s.x * C2LOG2E);
    r.y = EXP2F(s.y * C2LOG2E);
    r.z = EXP2F(s.z * C2LOG2E);
    r.w = EXP2F(s.w * C2LOG2E);
    reinterpret_cast<float4*>(eq)[i] = r;
  } else {
    const int j = (bid - 256) * 256 + threadIdx.x;  // float4 idx in k-half
    const int rl = j >> 5;            // local key row 0..2047
    const int b = rl >> 9, k = rl & 511;
    if (k >= valid_lens[b]) return;   // masked: never read downstream
    const int h4 = j & 31;
    float4 s = p[65536 + j];
#pragma unroll
    for (int jj = 1; jj < 8; ++jj) {
      const float4 v = p[65536 + j + jj * 131072];
      s.x += v.x; s.y += v.y; s.z += v.z; s.w += v.w;
    }
    float4 r;
    r.x = EXP2F(s.x * C2LOG2E);
    r.y = EXP2F(s.y * C2LOG2E);
    r.z = EXP2F(s.z * C2LOG2E);
    r.w = EXP2F(s.w * C2LOG2E);
    float* dst = ekT4 + ((((size_t)b * 32 + h4) << 9) + k) * 4;
    *reinterpret_cast<float4*>(dst) = r;
  }
}

// ---------------------------------------------------------------------------
// K3: Vt[b][v][k] = bf16(values[b][k][v])  (64x64 LDS transpose tiles)
// ---------------------------------------------------------------------------
__global__ __launch_bounds__(256) void vt_kernel(
    const float* __restrict__ values, unsigned short* __restrict__ Vt) {
  const int bid = blockIdx.x;
  const int b = bid >> 6;
  const int tile = bid & 63;
  const int k0 = (tile >> 3) << 6;
  const int v0 = (tile & 7) << 6;
  __shared__ unsigned short tl[64][72];
  const int t = threadIdx.x;
  const int kr = t >> 4, c4 = (t & 15) << 2;
#pragma unroll
  for (int pp = 0; pp < 4; ++pp) {
    const int k = kr + (pp << 4);
    const float4 v = *reinterpret_cast<const float4*>(
        values + ((size_t)(b * NK + k0 + k)) * DV + v0 + c4);
    tl[k][c4 + 0] = f2bf(v.x); tl[k][c4 + 1] = f2bf(v.y);
    tl[k][c4 + 2] = f2bf(v.z); tl[k][c4 + 3] = f2bf(v.w);
  }
  __syncthreads();
  const int vr = t >> 2, seg = t & 3;
  unsigned int pk[8];
#pragma unroll
  for (int i = 0; i < 8; ++i) {
    const int kc = (seg << 4) + (i << 1);
    pk[i] = (unsigned int)tl[kc][vr] | ((unsigned int)tl[kc + 1][vr] << 16);
  }
  unsigned short* dst = Vt + ((size_t)(b * NK + v0 + vr)) * NK + k0 + (seg << 4);
  *reinterpret_cast<uint4*>(dst) = make_uint4(pk[0], pk[1], pk[2], pk[3]);
  *reinterpret_cast<uint4*>(dst + 8) = make_uint4(pk[4], pk[5], pk[6], pk[7]);
}

// ---------------------------------------------------------------------------
// K4: scores + masked softmax. Block = (b, 4 q-rows), 512 thr, 512 blocks.
// Phase A loads ekT4 (one float4 per 4 h, coalesced 1KB/wave).
// Output: attnQ[b][q][k] in bf16 (k-contiguous, coalesced 2B stores).
// ---------------------------------------------------------------------------
__global__ __launch_bounds__(512) void scores_softmax_kernel(
    const float* __restrict__ eq, const float* __restrict__ ekT4,
    const float* __restrict__ Wv, const int* __restrict__ valid_lens,
    unsigned short* __restrict__ attnQ) {
  const int b = blockIdx.x >> 7;
  const int q0 = (blockIdx.x & 127) << 2;
  const int t = threadIdx.x;

  __shared__ __align__(16) float qs[4][HH];
  __shared__ __align__(16) float wv[HH];
  __shared__ __align__(16) float sc[4][NK];

  qs[t >> 7][t & 127] = eq[((size_t)(b * NQ + q0 + (t >> 7))) * HH + (t & 127)];
  if (t < HH) wv[t] = Wv[t];
  __syncthreads();

  const int vl = valid_lens[b];
  float s0 = 0.f, s1 = 0.f, s2 = 0.f, s3 = 0.f;

  if (t < vl) {
    const float* ekb4 = ekT4 + (((size_t)b * 16384 + t) << 2);  // [b][h4][k][4]
#pragma unroll 8
    for (int h4 = 0; h4 < 32; ++h4) {
      const float4 e4 = *reinterpret_cast<const float4*>(ekb4 + ((size_t)h4 << 11));
      const int h = h4 << 2;
      const float4 w4 = *reinterpret_cast<const float4*>(&wv[h]);
      const float4 qa = *reinterpret_cast<const float4*>(&qs[0][h]);
      const float4 qb = *reinterpret_cast<const float4*>(&qs[1][h]);
      const float4 qc = *reinterpret_cast<const float4*>(&qs[2][h]);
      const float4 qd = *reinterpret_cast<const float4*>(&qs[3][h]);
      float d, r;
      d = fmaf(qa.x, e4.x, 1.f); r = RCPF(d); s0 = fmaf(w4.x, r, s0);
      d = fmaf(qa.y, e4.y, 1.f); r = RCPF(d); s0 = fmaf(w4.y, r, s0);
      d = fmaf(qa.z, e4.z, 1.f); r = RCPF(d); s0 = fmaf(w4.z, r, s0);
      d = fmaf(qa.w, e4.w, 1.f); r = RCPF(d); s0 = fmaf(w4.w, r, s0);
      d = fmaf(qb.x, e4.x, 1.f); r = RCPF(d); s1 = fmaf(w4.x, r, s1);
      d = fmaf(qb.y, e4.y, 1.f); r = RCPF(d); s1 = fmaf(w4.y, r, s1);
      d = fmaf(qb.z, e4.z, 1.f); r = RCPF(d); s1 = fmaf(w4.z, r, s1);
      d = fmaf(qb.w, e4.w, 1.f); r = RCPF(d); s1 = fmaf(w4.w, r, s1);
      d = fmaf(qc.x, e4.x, 1.f); r = RCPF(d); s2 = fmaf(w4.x, r, s2);
      d = fmaf(qc.y, e4.y, 1.f); r = RCPF(d); s2 = fmaf(w4.y, r, s2);
      d = fmaf(qc.z, e4.z, 1.f); r = RCPF(d); s2 = fmaf(w4.z, r, s2);
      d = fmaf(qc.w, e4.w, 1.f); r = RCPF(d); s2 = fmaf(w4.w, r, s2);
      d = fmaf(qd.x, e4.x, 1.f); r = RCPF(d); s3 = fmaf(w4.x, r, s3);
      d = fmaf(qd.y, e4.y, 1.f); r = RCPF(d); s3 = fmaf(w4.y, r, s3);
      d = fmaf(qd.z, e4.z, 1.f); r = RCPF(d); s3 = fmaf(w4.z, r, s3);
      d = fmaf(qd.w, e4.w, 1.f); r = RCPF(d); s3 = fmaf(w4.w, r, s3);
    }
  }
  const bool act = (t < vl);
  sc[0][t] = act ? (-2.f * s0) : MASKV;
  sc[1][t] = act ? (-2.f * s1) : MASKV;
  sc[2][t] = act ? (-2.f * s2) : MASKV;
  sc[3][t] = act ? (-2.f * s3) : MASKV;
  __syncthreads();

  // softmax: wave w (<4) handles q-row w over all 512 keys
  const int w = t >> 6, l = t & 63;
  if (w < 4) {
    float v[8];
#pragma unroll
    for (int j = 0; j < 8; ++j) v[j] = sc[w][l + (j << 6)];
    float m = v[0];
#pragma unroll
    for (int j = 1; j < 8; ++j) m = fmaxf(m, v[j]);
#pragma unroll
    for (int off = 32; off > 0; off >>= 1) m = fmaxf(m, __shfl_xor(m, off, 64));
    float p[8], sum = 0.f;
#pragma unroll
    for (int j = 0; j < 8; ++j) {
      p[j] = __expf(v[j] - m);  // masked: underflows to exactly 0
      sum += p[j];
    }
#pragma unroll
    for (int off = 32; off > 0; off >>= 1) sum += __shfl_xor(sum, off, 64);
    const float inv = RCPF(sum);
#pragma unroll
    for (int j = 0; j < 8; ++j) sc[w][l + (j << 6)] = p[j] * inv;
  }
  __syncthreads();

  // write attnQ[b][q][k] bf16 (k = t): coalesced 2B stores, 4 rows
#pragma unroll
  for (int j = 0; j < 4; ++j)
    attnQ[((size_t)(b * NQ + q0 + j)) * NK + t] = f2bf(sc[j][t]);
}

// ---------------------------------------------------------------------------
// K5: PV via MFMA bf16: out[b][q][v] = sum_k attnQ[b][q][k] * Vt[b][v][k]
// 256 blocks = 4b x (8x8 tiles of 64x64). 256 thr = 4 waves, wave = 32x32
// quadrant = 2x2 MFMA 16x16x32 subtiles. K-loop ceil(vl/32); bf16 attn is
// exact 0 for masked k. Writes d_out directly (no partials, no reduce).
// ---------------------------------------------------------------------------
__global__ __launch_bounds__(256) void pv_mfma_kernel(
    const unsigned short* __restrict__ attnQ, const unsigned short* __restrict__ Vt,
    const int* __restrict__ valid_lens, float* __restrict__ out) {
  const int bid = blockIdx.x;
  const int b = bid & 3;            // adjacent blocks -> different batches
  const int tile = bid >> 2;        // 0..63
  const int q0 = (tile >> 3) << 6;
  const int v0 = (tile & 7) << 6;

  __shared__ __align__(16) unsigned short Als[64 * 72];  // [q][k], row 144B
  __shared__ __align__(16) unsigned short Bls[64 * 72];  // [v][k], row 144B

  const int t = threadIdx.x;
  const int w = t >> 6, l = t & 63;
  const int wq = w >> 1, wv = w & 1;
  const int lm = l & 15;
  const int lk = (l >> 4) << 3;     // k-offset within 32: 0,8,16,24

  const f32x4 z = {0.f, 0.f, 0.f, 0.f};
  f32x4 acc[2][2] = {{z, z}, {z, z}};

  const int vl = valid_lens[b];
  const int nkt = (vl + 31) >> 5;

  const int sq = t >> 2, seg = t & 3;  // staging: row sq, 16B segment seg
  const unsigned short* arow = attnQ + ((size_t)(b * NQ + q0 + sq)) * NK;
  const unsigned short* brow = Vt + ((size_t)(b * NK + v0 + sq)) * NK;
  unsigned short* alds = &Als[sq * 72 + (seg << 3)];
  unsigned short* blds = &Bls[sq * 72 + (seg << 3)];

  for (int kt = 0; kt < nkt; ++kt) {
    const int k0 = kt << 5;
    *reinterpret_cast<bf16x8*>(alds) =
        *reinterpret_cast<const bf16x8*>(arow + k0 + (seg << 3));
    *reinterpret_cast<bf16x8*>(blds) =
        *reinterpret_cast<const bf16x8*>(brow + k0 + (seg << 3));
    __syncthreads();

    bf16x8 af[2], bf[2];
#pragma unroll
    for (int mq = 0; mq < 2; ++mq)
      af[mq] = *reinterpret_cast<const bf16x8*>(
          &Als[(wq * 32 + mq * 16 + lm) * 72 + lk]);
#pragma unroll
    for (int nv = 0; nv < 2; ++nv)
      bf[nv] = *reinterpret_cast<const bf16x8*>(
          &Bls[(wv * 32 + nv * 16 + lm) * 72 + lk]);
#pragma unroll
    for (int mq = 0; mq < 2; ++mq)
#pragma unroll
      for (int nv = 0; nv < 2; ++nv)
        acc[mq][nv] = __builtin_amdgcn_mfma_f32_16x16x32_bf16(
            af[mq], bf[nv], acc[mq][nv], 0, 0, 0);
    __syncthreads();
  }

  // epilogue: D lane mapping col=lane&15, row=(lane>>4)*4+j  [m89-verified]
  const int rbase = (l >> 4) << 2;
#pragma unroll
  for (int mq = 0; mq < 2; ++mq) {
#pragma unroll
    for (int nv = 0; nv < 2; ++nv) {
      const int qg = q0 + wq * 32 + mq * 16 + rbase;
      const int vg = v0 + wv * 32 + nv * 16 + lm;
#pragma unroll
      for (int j = 0; j < 4; ++j)
        out[((size_t)(b * NQ + qg + j)) * DV + vg] = acc[mq][nv][j];
    }
  }
}

extern "C" void kernel_launch(void* const* d_in, const int* in_sizes, int n_in,
                              void* d_out, int out_size, void* d_ws, size_t ws_size,
                              hipStream_t stream) {
  (void)in_sizes; (void)n_in; (void)out_size; (void)ws_size;
  const float* queries = (const float*)d_in[0];
  const float* keys    = (const float*)d_in[1];
  const float* values  = (const float*)d_in[2];
  const float* Wq      = (const float*)d_in[3];
  const float* Wk      = (const float*)d_in[4];
  const float* Wv      = (const float*)d_in[5];
  const int*   vlens   = (const int*)d_in[6];
  float* out = (float*)d_out;
  float* ws = (float*)d_ws;

  // ws floats: eq 262144 | ekT4 262144 | attnQ (1M ushort = 524288 f)
  //          | Vt (1M ushort = 524288 f) | projpart 4194304
  float* eq       = ws;
  float* ekT4     = ws + 262144;
  unsigned short* attnQ = (unsigned short*)(ws + 524288);
  unsigned short* Vt    = (unsigned short*)(ws + 1048576);
  float* projpart = ws + 1572864;

  vt_kernel<<<256, 256, 0, stream>>>(values, Vt);
  proj_gemm_kernel<<<512, 256, 0, stream>>>(queries, keys, Wq, Wk, vlens, projpart);
  proj_reduce_kernel<<<512, 256, 0, stream>>>(projpart, vlens, eq, ekT4);
  scores_softmax_kernel<<<512, 512, 0, stream>>>(eq, ekT4, Wv, vlens, attnQ);
  pv_mfma_kernel<<<256, 256, 0, stream>>>(attnQ, Vt, vlens, out);
}

// Round 8
// 51.101 us; speedup vs baseline: 1.4561x; 1.0556x over previous
//
#include <hip/hip_runtime.h>

#ifndef __has_builtin
#define __has_builtin(x) 0
#endif

#if __has_builtin(__builtin_amdgcn_exp2f)
#define EXP2F(x) __builtin_amdgcn_exp2f(x)
#else
#define EXP2F(x) exp2f(x)
#endif
#if __has_builtin(__builtin_amdgcn_rcpf)
#define RCPF(x) __builtin_amdgcn_rcpf(x)
#else
#define RCPF(x) (1.0f / (x))
#endif

static constexpr int NB = 4, NQ = 512, NK = 512, DD = 512, HH = 128, DV = 512;
static constexpr float MASKV = -1e6f;
static constexpr float C2LOG2E = 2.885390081777926814f;  // 2*log2(e)

typedef __attribute__((ext_vector_type(8))) short bf16x8;
typedef __attribute__((ext_vector_type(4))) float f32x4;

__device__ __forceinline__ unsigned short f2bf(float x) {  // RNE f32->bf16
  unsigned int u = __float_as_uint(x);
  u += 0x7FFFu + ((u >> 16) & 1u);
  return (unsigned short)(u >> 16);
}

// ---------------------------------------------------------------------------
// K1: full-K projection + exp2 epilogue, one kernel, no partials.
// 256 blocks x 16 rows (rows 0..2047 = queries -> eq flat,
// rows 2048..4095 = keys -> ekT4[b][h4][k][4] transposed).
// Per k-tile (64): stage A[16][68] + W[64][128] in LDS; thread = (h4 group
// hg = t&31, row pair rg = t>>5), acc[2][4]. Masked key blocks skip.
// ---------------------------------------------------------------------------
__global__ __launch_bounds__(256) void proj_full_kernel(
    const float* __restrict__ queries, const float* __restrict__ keys,
    const float* __restrict__ Wq, const float* __restrict__ Wk,
    const int* __restrict__ valid_lens,
    float* __restrict__ eq, float* __restrict__ ekT4) {
  const int row0 = blockIdx.x << 4;
  const bool isK = row0 >= 2048;
  int b = 0, kloc = 0;
  const float* inb;
  const float* W;
  if (isK) {
    const int local = row0 - 2048;
    b = local >> 9;
    kloc = local & 511;
    if (kloc >= valid_lens[b]) return;  // whole block masked, never read
    inb = keys + (size_t)local * DD;
    W = Wk;
  } else {
    inb = queries + (size_t)row0 * DD;
    W = Wq;
  }

  __shared__ __align__(16) float At[16][68];
  __shared__ __align__(16) float Wt[64][128];

  const int t = threadIdx.x;
  const int hg = t & 31;   // h4 group: h = hg*4 .. +3
  const int rg = t >> 5;   // row pair: rows rg*2, rg*2+1

  float acc[2][4] = {{0.f, 0.f, 0.f, 0.f}, {0.f, 0.f, 0.f, 0.f}};

  for (int kt = 0; kt < 8; ++kt) {
    const int k0 = kt << 6;
    {  // stage A: 16 rows x 64 k
      const int r = t >> 4, c4 = (t & 15) << 2;
      *reinterpret_cast<float4*>(&At[r][c4]) =
          *reinterpret_cast<const float4*>(inb + (size_t)r * DD + k0 + c4);
    }
#pragma unroll
    for (int f = 0; f < 8; ++f) {  // stage W: 64 k x 128 h
      const int idx = t + (f << 8);
      const int dk = idx >> 5, c4 = (idx & 31) << 2;
      *reinterpret_cast<float4*>(&Wt[dk][c4]) =
          *reinterpret_cast<const float4*>(W + (size_t)(k0 + dk) * HH + c4);
    }
    __syncthreads();
#pragma unroll 8
    for (int kk = 0; kk < 64; ++kk) {
      const float a0 = At[(rg << 1) + 0][kk];
      const float a1 = At[(rg << 1) + 1][kk];
      const float4 w4 = *reinterpret_cast<const float4*>(&Wt[kk][hg << 2]);
      acc[0][0] = fmaf(a0, w4.x, acc[0][0]);
      acc[0][1] = fmaf(a0, w4.y, acc[0][1]);
      acc[0][2] = fmaf(a0, w4.z, acc[0][2]);
      acc[0][3] = fmaf(a0, w4.w, acc[0][3]);
      acc[1][0] = fmaf(a1, w4.x, acc[1][0]);
      acc[1][1] = fmaf(a1, w4.y, acc[1][1]);
      acc[1][2] = fmaf(a1, w4.z, acc[1][2]);
      acc[1][3] = fmaf(a1, w4.w, acc[1][3]);
    }
    __syncthreads();
  }

#pragma unroll
  for (int j = 0; j < 2; ++j) {
    float4 e;
    e.x = EXP2F(acc[j][0] * C2LOG2E);
    e.y = EXP2F(acc[j][1] * C2LOG2E);
    e.z = EXP2F(acc[j][2] * C2LOG2E);
    e.w = EXP2F(acc[j][3] * C2LOG2E);
    const int r = (rg << 1) + j;
    if (isK) {
      // ekT4[b][h4=hg][k=kloc+r][4]
      float* dst = ekT4 + ((((size_t)b * 32 + hg) << 9) + (kloc + r)) * 4;
      *reinterpret_cast<float4*>(dst) = e;
    } else {
      *reinterpret_cast<float4*>(eq + (size_t)(row0 + r) * HH + (hg << 2)) = e;
    }
  }
}

// ---------------------------------------------------------------------------
// K2: scores + masked softmax. Block = (b, 4 q-rows), 512 thr, 512 blocks.
// Phase A loads ekT4 coalesced (one float4 per 4 h, 1KB/wave).
// Output: attnQ[b][q][k] bf16 (k-contiguous).  (R7-proven)
// ---------------------------------------------------------------------------
__global__ __launch_bounds__(512) void scores_softmax_kernel(
    const float* __restrict__ eq, const float* __restrict__ ekT4,
    const float* __restrict__ Wv, const int* __restrict__ valid_lens,
    unsigned short* __restrict__ attnQ) {
  const int b = blockIdx.x >> 7;
  const int q0 = (blockIdx.x & 127) << 2;
  const int t = threadIdx.x;

  __shared__ __align__(16) float qs[4][HH];
  __shared__ __align__(16) float wv[HH];
  __shared__ __align__(16) float sc[4][NK];

  qs[t >> 7][t & 127] = eq[((size_t)(b * NQ + q0 + (t >> 7))) * HH + (t & 127)];
  if (t < HH) wv[t] = Wv[t];
  __syncthreads();

  const int vl = valid_lens[b];
  float s0 = 0.f, s1 = 0.f, s2 = 0.f, s3 = 0.f;

  if (t < vl) {
    const float* ekb4 = ekT4 + (((size_t)b * 16384 + t) << 2);  // [b][h4][k][4]
#pragma unroll 8
    for (int h4 = 0; h4 < 32; ++h4) {
      const float4 e4 = *reinterpret_cast<const float4*>(ekb4 + ((size_t)h4 << 11));
      const int h = h4 << 2;
      const float4 w4 = *reinterpret_cast<const float4*>(&wv[h]);
      const float4 qa = *reinterpret_cast<const float4*>(&qs[0][h]);
      const float4 qb = *reinterpret_cast<const float4*>(&qs[1][h]);
      const float4 qc = *reinterpret_cast<const float4*>(&qs[2][h]);
      const float4 qd = *reinterpret_cast<const float4*>(&qs[3][h]);
      float d, r;
      d = fmaf(qa.x, e4.x, 1.f); r = RCPF(d); s0 = fmaf(w4.x, r, s0);
      d = fmaf(qa.y, e4.y, 1.f); r = RCPF(d); s0 = fmaf(w4.y, r, s0);
      d = fmaf(qa.z, e4.z, 1.f); r = RCPF(d); s0 = fmaf(w4.z, r, s0);
      d = fmaf(qa.w, e4.w, 1.f); r = RCPF(d); s0 = fmaf(w4.w, r, s0);
      d = fmaf(qb.x, e4.x, 1.f); r = RCPF(d); s1 = fmaf(w4.x, r, s1);
      d = fmaf(qb.y, e4.y, 1.f); r = RCPF(d); s1 = fmaf(w4.y, r, s1);
      d = fmaf(qb.z, e4.z, 1.f); r = RCPF(d); s1 = fmaf(w4.z, r, s1);
      d = fmaf(qb.w, e4.w, 1.f); r = RCPF(d); s1 = fmaf(w4.w, r, s1);
      d = fmaf(qc.x, e4.x, 1.f); r = RCPF(d); s2 = fmaf(w4.x, r, s2);
      d = fmaf(qc.y, e4.y, 1.f); r = RCPF(d); s2 = fmaf(w4.y, r, s2);
      d = fmaf(qc.z, e4.z, 1.f); r = RCPF(d); s2 = fmaf(w4.z, r, s2);
      d = fmaf(qc.w, e4.w, 1.f); r = RCPF(d); s2 = fmaf(w4.w, r, s2);
      d = fmaf(qd.x, e4.x, 1.f); r = RCPF(d); s3 = fmaf(w4.x, r, s3);
      d = fmaf(qd.y, e4.y, 1.f); r = RCPF(d); s3 = fmaf(w4.y, r, s3);
      d = fmaf(qd.z, e4.z, 1.f); r = RCPF(d); s3 = fmaf(w4.z, r, s3);
      d = fmaf(qd.w, e4.w, 1.f); r = RCPF(d); s3 = fmaf(w4.w, r, s3);
    }
  }
  const bool act = (t < vl);
  sc[0][t] = act ? (-2.f * s0) : MASKV;
  sc[1][t] = act ? (-2.f * s1) : MASKV;
  sc[2][t] = act ? (-2.f * s2) : MASKV;
  sc[3][t] = act ? (-2.f * s3) : MASKV;
  __syncthreads();

  const int w = t >> 6, l = t & 63;
  if (w < 4) {
    float v[8];
#pragma unroll
    for (int j = 0; j < 8; ++j) v[j] = sc[w][l + (j << 6)];
    float m = v[0];
#pragma unroll
    for (int j = 1; j < 8; ++j) m = fmaxf(m, v[j]);
#pragma unroll
    for (int off = 32; off > 0; off >>= 1) m = fmaxf(m, __shfl_xor(m, off, 64));
    float p[8], sum = 0.f;
#pragma unroll
    for (int j = 0; j < 8; ++j) {
      p[j] = __expf(v[j] - m);  // masked: underflows to exactly 0
      sum += p[j];
    }
#pragma unroll
    for (int off = 32; off > 0; off >>= 1) sum += __shfl_xor(sum, off, 64);
    const float inv = RCPF(sum);
#pragma unroll
    for (int j = 0; j < 8; ++j) sc[w][l + (j << 6)] = p[j] * inv;
  }
  __syncthreads();

#pragma unroll
  for (int j = 0; j < 4; ++j)
    attnQ[((size_t)(b * NQ + q0 + j)) * NK + t] = f2bf(sc[j][t]);
}

// ---------------------------------------------------------------------------
// K3: PV via MFMA bf16, V-transpose INLINED into staging (no Vt kernel).
// out[b][q][v] = sum_k attnQ[b][q][k] * bf16(values[b][k][v]).
// 256 blocks = 4b x 64 tiles of 64q x 64v; 4 waves, 2x2 MFMA 16x16x32 each.
// ---------------------------------------------------------------------------
__global__ __launch_bounds__(256) void pv_mfma_kernel(
    const unsigned short* __restrict__ attnQ, const float* __restrict__ values,
    const int* __restrict__ valid_lens, float* __restrict__ out) {
  const int bid = blockIdx.x;
  const int b = bid & 3;            // adjacent blocks -> different batches
  const int tile = bid >> 2;
  const int q0 = (tile >> 3) << 6;
  const int v0 = (tile & 7) << 6;

  __shared__ __align__(16) unsigned short Als[64 * 72];  // [q][k]
  __shared__ __align__(16) unsigned short Bls[64 * 72];  // [v][k]

  const int t = threadIdx.x;
  const int w = t >> 6, l = t & 63;
  const int wq = w >> 1, wv = w & 1;
  const int lm = l & 15;
  const int lk = (l >> 4) << 3;

  const f32x4 z = {0.f, 0.f, 0.f, 0.f};
  f32x4 acc[2][2] = {{z, z}, {z, z}};

  const int vl = valid_lens[b];
  const int nkt = (vl + 31) >> 5;

  // A staging: thread -> (q row sq, 16B k-segment seg)
  const int sq = t >> 2, seg = t & 3;
  const unsigned short* arow = attnQ + ((size_t)(b * NQ + q0 + sq)) * NK;
  unsigned short* alds = &Als[sq * 72 + (seg << 3)];
  // V staging: thread -> (k row vk (+16), v col group vc4); transpose + bf16
  const int vk = t >> 4, vc4 = (t & 15) << 2;
  const float* vbase = values + ((size_t)(b * NK)) * DV + v0 + vc4;

  for (int kt = 0; kt < nkt; ++kt) {
    const int k0 = kt << 5;
    *reinterpret_cast<bf16x8*>(alds) =
        *reinterpret_cast<const bf16x8*>(arow + k0 + (seg << 3));
#pragma unroll
    for (int p = 0; p < 2; ++p) {
      const int kr = vk + (p << 4);
      const float4 v4 = *reinterpret_cast<const float4*>(vbase + (size_t)(k0 + kr) * DV);
      Bls[(vc4 + 0) * 72 + kr] = f2bf(v4.x);
      Bls[(vc4 + 1) * 72 + kr] = f2bf(v4.y);
      Bls[(vc4 + 2) * 72 + kr] = f2bf(v4.z);
      Bls[(vc4 + 3) * 72 + kr] = f2bf(v4.w);
    }
    __syncthreads();

    bf16x8 af[2], bfr[2];
#pragma unroll
    for (int mq = 0; mq < 2; ++mq)
      af[mq] = *reinterpret_cast<const bf16x8*>(
          &Als[(wq * 32 + mq * 16 + lm) * 72 + lk]);
#pragma unroll
    for (int nv = 0; nv < 2; ++nv)
      bfr[nv] = *reinterpret_cast<const bf16x8*>(
          &Bls[(wv * 32 + nv * 16 + lm) * 72 + lk]);
#pragma unroll
    for (int mq = 0; mq < 2; ++mq)
#pragma unroll
      for (int nv = 0; nv < 2; ++nv)
        acc[mq][nv] = __builtin_amdgcn_mfma_f32_16x16x32_bf16(
            af[mq], bfr[nv], acc[mq][nv], 0, 0, 0);
    __syncthreads();
  }

  // epilogue: D lane mapping col=lane&15, row=(lane>>4)*4+j  [m89-verified]
  const int rbase = (l >> 4) << 2;
#pragma unroll
  for (int mq = 0; mq < 2; ++mq) {
#pragma unroll
    for (int nv = 0; nv < 2; ++nv) {
      const int qg = q0 + wq * 32 + mq * 16 + rbase;
      const int vg = v0 + wv * 32 + nv * 16 + lm;
#pragma unroll
      for (int j = 0; j < 4; ++j)
        out[((size_t)(b * NQ + qg + j)) * DV + vg] = acc[mq][nv][j];
    }
  }
}

extern "C" void kernel_launch(void* const* d_in, const int* in_sizes, int n_in,
                              void* d_out, int out_size, void* d_ws, size_t ws_size,
                              hipStream_t stream) {
  (void)in_sizes; (void)n_in; (void)out_size; (void)ws_size;
  const float* queries = (const float*)d_in[0];
  const float* keys    = (const float*)d_in[1];
  const float* values  = (const float*)d_in[2];
  const float* Wq      = (const float*)d_in[3];
  const float* Wk      = (const float*)d_in[4];
  const float* Wv      = (const float*)d_in[5];
  const int*   vlens   = (const int*)d_in[6];
  float* out = (float*)d_out;
  float* ws = (float*)d_ws;

  // ws floats: eq 262144 | ekT4 262144 | attnQ (1M ushort = 524288 f)
  float* eq   = ws;
  float* ekT4 = ws + 262144;
  unsigned short* attnQ = (unsigned short*)(ws + 524288);

  proj_full_kernel<<<256, 256, 0, stream>>>(queries, keys, Wq, Wk, vlens, eq, ekT4);
  scores_softmax_kernel<<<512, 512, 0, stream>>>(eq, ekT4, Wv, vlens, attnQ);
  pv_mfma_kernel<<<256, 256, 0, stream>>>(attnQ, values, vlens, out);
}

// Round 10
// 46.825 us; speedup vs baseline: 1.5891x; 1.0913x over previous
//
#include <hip/hip_runtime.h>

#ifndef __has_builtin
#define __has_builtin(x) 0
#endif

#if __has_builtin(__builtin_amdgcn_exp2f)
#define EXP2F(x) __builtin_amdgcn_exp2f(x)
#else
#define EXP2F(x) exp2f(x)
#endif
#if __has_builtin(__builtin_amdgcn_rcpf)
#define RCPF(x) __builtin_amdgcn_rcpf(x)
#else
#define RCPF(x) (1.0f / (x))
#endif

static constexpr int NB = 4, NQ = 512, NK = 512, DD = 512, HH = 128, DV = 512;
static constexpr float MASKV = -1e6f;
static constexpr float C2LOG2E = 2.885390081777926814f;  // 2*log2(e)

typedef __attribute__((ext_vector_type(8))) short bf16x8;
typedef __attribute__((ext_vector_type(4))) float f32x4;

__device__ __forceinline__ unsigned short f2bf(float x) {  // RNE f32->bf16
  unsigned int u = __float_as_uint(x);
  u += 0x7FFFu + ((u >> 16) & 1u);
  return (unsigned short)(u >> 16);
}

// ---------------------------------------------------------------------------
// K1: tiled GEMM for both projections (R3-proven). Stacked rows
// (0..2047 q, 2048.. keys), 8-way K-split, tile 64x128, 256 thr,
// 4x8 micro-tile. Masked key tiles skip.
// ---------------------------------------------------------------------------
__global__ __launch_bounds__(256) void proj_gemm_kernel(
    const float* __restrict__ queries, const float* __restrict__ keys,
    const float* __restrict__ Wq, const float* __restrict__ Wk,
    const int* __restrict__ valid_lens, float* __restrict__ projpart) {
  const int mt = blockIdx.x >> 3;
  const int ks = blockIdx.x & 7;
  const int row0 = mt << 6;
  const int k0 = ks << 6;
  const float* inb;
  const float* W;
  if (row0 >= 2048) {
    const int local = row0 - 2048;
    if ((local & 511) >= valid_lens[local >> 9]) return;  // never consumed
    inb = keys + (size_t)local * DD;
    W = Wk;
  } else {
    inb = queries + (size_t)row0 * DD;
    W = Wq;
  }

  __shared__ float aS[64][65];
  __shared__ __align__(16) float bS[64][128];

  const int t = threadIdx.x;
#pragma unroll
  for (int f = 0; f < 4; ++f) {
    const int idx = t + (f << 8);
    const int r = idx >> 4, d0 = (idx & 15) << 2;
    const float4 v = *reinterpret_cast<const float4*>(inb + (size_t)r * DD + k0 + d0);
    aS[r][d0] = v.x; aS[r][d0 + 1] = v.y; aS[r][d0 + 2] = v.z; aS[r][d0 + 3] = v.w;
  }
#pragma unroll
  for (int f = 0; f < 8; ++f) {
    const int idx = t + (f << 8);
    const int dk = idx >> 5, c4 = (idx & 31) << 2;
    *reinterpret_cast<float4*>(&bS[dk][c4]) =
        *reinterpret_cast<const float4*>(W + (size_t)(k0 + dk) * HH + c4);
  }
  __syncthreads();

  const int tv = t & 15, tr = t >> 4;
  float acc[4][8];
#pragma unroll
  for (int i = 0; i < 4; ++i)
#pragma unroll
    for (int j = 0; j < 8; ++j) acc[i][j] = 0.f;

#pragma unroll 8
  for (int dk = 0; dk < 64; ++dk) {
    const float av[4] = {aS[(tr << 2) + 0][dk], aS[(tr << 2) + 1][dk],
                         aS[(tr << 2) + 2][dk], aS[(tr << 2) + 3][dk]};
    const float4 b0 = *reinterpret_cast<const float4*>(&bS[dk][tv << 2]);
    const float4 b1 = *reinterpret_cast<const float4*>(&bS[dk][64 + (tv << 2)]);
    const float bv[8] = {b0.x, b0.y, b0.z, b0.w, b1.x, b1.y, b1.z, b1.w};
#pragma unroll
    for (int i = 0; i < 4; ++i)
#pragma unroll
      for (int j = 0; j < 8; ++j) acc[i][j] = fmaf(av[i], bv[j], acc[i][j]);
  }

  float* pb = projpart + ((size_t)ks << 19) + (size_t)row0 * HH;
#pragma unroll
  for (int i = 0; i < 4; ++i) {
    float* rowp = pb + (size_t)((tr << 2) + i) * HH;
    *reinterpret_cast<float4*>(rowp + (tv << 2)) =
        make_float4(acc[i][0], acc[i][1], acc[i][2], acc[i][3]);
    *reinterpret_cast<float4*>(rowp + 64 + (tv << 2)) =
        make_float4(acc[i][4], acc[i][5], acc[i][6], acc[i][7]);
  }
}

// ---------------------------------------------------------------------------
// K2 (combo): 768 blocks.
//   bid 0..255   : q-reduce  -> eq[row][h] = exp2(C*sum)
//   bid 256..511 : k-reduce  -> ekT4[b][h4][k][4] (transposed; masked skip)
//   bid 512..767 : V transpose -> Vt[b][v][k] bf16 (64x64 LDS tiles)
// ---------------------------------------------------------------------------
__global__ __launch_bounds__(256) void combo_kernel(
    const float* __restrict__ projpart, const float* __restrict__ values,
    const int* __restrict__ valid_lens,
    float* __restrict__ eq, float* __restrict__ ekT4,
    unsigned short* __restrict__ Vt) {
  const int bid = blockIdx.x;
  const int t = threadIdx.x;
  __shared__ unsigned short tl[64][72];

  if (bid < 256) {
    const float4* p = reinterpret_cast<const float4*>(projpart);
    const int i = bid * 256 + t;  // float4 idx into q-half (65536)
    float4 s = p[i];
#pragma unroll
    for (int j = 1; j < 8; ++j) {
      const float4 v = p[i + j * 131072];
      s.x += v.x; s.y += v.y; s.z += v.z; s.w += v.w;
    }
    float4 r;
    r.x = EXP2F(s.x * C2LOG2E);
    r.y = EXP2F(s.y * C2LOG2E);
    r.z = EXP2F(s.z * C2LOG2E);
    r.w = EXP2F(s.w * C2LOG2E);
    reinterpret_cast<float4*>(eq)[i] = r;
  } else if (bid < 512) {
    const float4* p = reinterpret_cast<const float4*>(projpart);
    const int j = (bid - 256) * 256 + t;  // float4 idx in k-half
    const int rl = j >> 5;                // local key row 0..2047
    const int b = rl >> 9, k = rl & 511;
    if (k >= valid_lens[b]) return;       // masked: never read downstream
    const int h4 = j & 31;
    float4 s = p[65536 + j];
#pragma unroll
    for (int jj = 1; jj < 8; ++jj) {
      const float4 v = p[65536 + j + jj * 131072];
      s.x += v.x; s.y += v.y; s.z += v.z; s.w += v.w;
    }
    float4 r;
    r.x = EXP2F(s.x * C2LOG2E);
    r.y = EXP2F(s.y * C2LOG2E);
    r.z = EXP2F(s.z * C2LOG2E);
    r.w = EXP2F(s.w * C2LOG2E);
    *reinterpret_cast<float4*>(ekT4 + ((((size_t)b * 32 + h4) << 9) + k) * 4) = r;
  } else {
    const int vb = bid - 512;
    const int b = vb >> 6;
    const int tile = vb & 63;
    const int k0 = (tile >> 3) << 6;
    const int v0 = (tile & 7) << 6;
    const int kr = t >> 4, c4 = (t & 15) << 2;
#pragma unroll
    for (int pp = 0; pp < 4; ++pp) {
      const int k = kr + (pp << 4);
      const float4 v = *reinterpret_cast<const float4*>(
          values + ((size_t)(b * NK + k0 + k)) * DV + v0 + c4);
      tl[k][c4 + 0] = f2bf(v.x); tl[k][c4 + 1] = f2bf(v.y);
      tl[k][c4 + 2] = f2bf(v.z); tl[k][c4 + 3] = f2bf(v.w);
    }
    __syncthreads();
    const int vr = t >> 2, seg = t & 3;
    unsigned int pk[8];
#pragma unroll
    for (int i = 0; i < 8; ++i) {
      const int kc = (seg << 4) + (i << 1);
      pk[i] = (unsigned int)tl[kc][vr] | ((unsigned int)tl[kc + 1][vr] << 16);
    }
    unsigned short* dst = Vt + ((size_t)(b * NK + v0 + vr)) * NK + k0 + (seg << 4);
    *reinterpret_cast<uint4*>(dst) = make_uint4(pk[0], pk[1], pk[2], pk[3]);
    *reinterpret_cast<uint4*>(dst + 8) = make_uint4(pk[4], pk[5], pk[6], pk[7]);
  }
}

// ---------------------------------------------------------------------------
// K3: scores + masked softmax, 1024 threads (h-split x2 -> 100% occupancy).
// Block = (b, 4 q-rows), 512 blocks. Thread = (key kk = t&511, h-half hh).
// Each thread: 16 h4 iters over its h-half; partials combined in LDS.
// score = -2*sum_h w_h/(1+eq*ek). Output attnQ[b][q][k] bf16.
// ---------------------------------------------------------------------------
__global__ __launch_bounds__(1024) void scores_softmax_kernel(
    const float* __restrict__ eq, const float* __restrict__ ekT4,
    const float* __restrict__ Wv, const int* __restrict__ valid_lens,
    unsigned short* __restrict__ attnQ) {
  const int b = blockIdx.x >> 7;
  const int q0 = (blockIdx.x & 127) << 2;
  const int t = threadIdx.x;
  const int kk = t & 511, hh = t >> 9;

  __shared__ __align__(16) float qs[4][HH];
  __shared__ __align__(16) float wv[HH];
  __shared__ __align__(16) float scp[2][4][NK];  // 16 KB partials

  if (t < 512) {
    qs[t >> 7][t & 127] = eq[((size_t)(b * NQ + q0 + (t >> 7))) * HH + (t & 127)];
  } else if (t < 640) {
    wv[t - 512] = Wv[t - 512];
  }
  __syncthreads();

  const int vl = valid_lens[b];
  float s0 = 0.f, s1 = 0.f, s2 = 0.f, s3 = 0.f;

  if (kk < vl) {
    // ekT4[b][h4][k][4]: base at h4 = hh*16, per-iter stride 2048 floats
    const float* ekb4 = ekT4 + (((size_t)(b * 32 + hh * 16) << 9) + kk) * 4;
#pragma unroll 8
    for (int i = 0; i < 16; ++i) {
      const float4 e4 = *reinterpret_cast<const float4*>(ekb4 + ((size_t)i << 11));
      const int h = (hh * 16 + i) << 2;
      const float4 w4 = *reinterpret_cast<const float4*>(&wv[h]);
      const float4 qa = *reinterpret_cast<const float4*>(&qs[0][h]);
      const float4 qb = *reinterpret_cast<const float4*>(&qs[1][h]);
      const float4 qc = *reinterpret_cast<const float4*>(&qs[2][h]);
      const float4 qd = *reinterpret_cast<const float4*>(&qs[3][h]);
      float d, r;
      d = fmaf(qa.x, e4.x, 1.f); r = RCPF(d); s0 = fmaf(w4.x, r, s0);
      d = fmaf(qa.y, e4.y, 1.f); r = RCPF(d); s0 = fmaf(w4.y, r, s0);
      d = fmaf(qa.z, e4.z, 1.f); r = RCPF(d); s0 = fmaf(w4.z, r, s0);
      d = fmaf(qa.w, e4.w, 1.f); r = RCPF(d); s0 = fmaf(w4.w, r, s0);
      d = fmaf(qb.x, e4.x, 1.f); r = RCPF(d); s1 = fmaf(w4.x, r, s1);
      d = fmaf(qb.y, e4.y, 1.f); r = RCPF(d); s1 = fmaf(w4.y, r, s1);
      d = fmaf(qb.z, e4.z, 1.f); r = RCPF(d); s1 = fmaf(w4.z, r, s1);
      d = fmaf(qb.w, e4.w, 1.f); r = RCPF(d); s1 = fmaf(w4.w, r, s1);
      d = fmaf(qc.x, e4.x, 1.f); r = RCPF(d); s2 = fmaf(w4.x, r, s2);
      d = fmaf(qc.y, e4.y, 1.f); r = RCPF(d); s2 = fmaf(w4.y, r, s2);
      d = fmaf(qc.z, e4.z, 1.f); r = RCPF(d); s2 = fmaf(w4.z, r, s2);
      d = fmaf(qc.w, e4.w, 1.f); r = RCPF(d); s2 = fmaf(w4.w, r, s2);
      d = fmaf(qd.x, e4.x, 1.f); r = RCPF(d); s3 = fmaf(w4.x, r, s3);
      d = fmaf(qd.y, e4.y, 1.f); r = RCPF(d); s3 = fmaf(w4.y, r, s3);
      d = fmaf(qd.z, e4.z, 1.f); r = RCPF(d); s3 = fmaf(w4.z, r, s3);
      d = fmaf(qd.w, e4.w, 1.f); r = RCPF(d); s3 = fmaf(w4.w, r, s3);
    }
  }
  scp[hh][0][kk] = s0;
  scp[hh][1][kk] = s1;
  scp[hh][2][kk] = s2;
  scp[hh][3][kk] = s3;
  __syncthreads();

  // softmax: waves 0..3 (t<256) handle q-rows 0..3, combining the h-halves
  if (t < 256) {
    const int w = t >> 6, l = t & 63;
    float v[8];
#pragma unroll
    for (int j = 0; j < 8; ++j) {
      const int k = l + (j << 6);
      const float sv = scp[0][w][k] + scp[1][w][k];
      v[j] = (k < vl) ? (-2.f * sv) : MASKV;
    }
    float m = v[0];
#pragma unroll
    for (int j = 1; j < 8; ++j) m = fmaxf(m, v[j]);
#pragma unroll
    for (int off = 32; off > 0; off >>= 1) m = fmaxf(m, __shfl_xor(m, off, 64));
    float p[8], sum = 0.f;
#pragma unroll
    for (int j = 0; j < 8; ++j) {
      p[j] = __expf(v[j] - m);  // masked: underflows to exactly 0
      sum += p[j];
    }
#pragma unroll
    for (int off = 32; off > 0; off >>= 1) sum += __shfl_xor(sum, off, 64);
    const float inv = RCPF(sum);
#pragma unroll
    for (int j = 0; j < 8; ++j) scp[0][w][l + (j << 6)] = p[j] * inv;
  }
  __syncthreads();

  if (t < 512) {
#pragma unroll
    for (int j = 0; j < 4; ++j)
      attnQ[((size_t)(b * NQ + q0 + j)) * NK + t] = f2bf(scp[0][j][t]);
  }
}

// ---------------------------------------------------------------------------
// K4: PV via MFMA bf16 (R7-proven, pre-transposed Vt).
// out[b][q][v] = sum_k attnQ[b][q][k] * Vt[b][v][k].
// 256 blocks = 4b x 64 tiles of 64q x 64v; 4 waves, 2x2 MFMA 16x16x32 each.
// ---------------------------------------------------------------------------
__global__ __launch_bounds__(256) void pv_mfma_kernel(
    const unsigned short* __restrict__ attnQ, const unsigned short* __restrict__ Vt,
    const int* __restrict__ valid_lens, float* __restrict__ out) {
  const int bid = blockIdx.x;
  const int b = bid & 3;            // adjacent blocks -> different batches
  const int tile = bid >> 2;
  const int q0 = (tile >> 3) << 6;
  const int v0 = (tile & 7) << 6;

  __shared__ __align__(16) unsigned short Als[64 * 72];  // [q][k]
  __shared__ __align__(16) unsigned short Bls[64 * 72];  // [v][k]

  const int t = threadIdx.x;
  const int w = t >> 6, l = t & 63;
  const int wq = w >> 1, wv = w & 1;
  const int lm = l & 15;
  const int lk = (l >> 4) << 3;

  const f32x4 z = {0.f, 0.f, 0.f, 0.f};
  f32x4 acc[2][2] = {{z, z}, {z, z}};

  const int vl = valid_lens[b];
  const int nkt = (vl + 31) >> 5;

  const int sq = t >> 2, seg = t & 3;
  const unsigned short* arow = attnQ + ((size_t)(b * NQ + q0 + sq)) * NK;
  const unsigned short* brow = Vt + ((size_t)(b * NK + v0 + sq)) * NK;
  unsigned short* alds = &Als[sq * 72 + (seg << 3)];
  unsigned short* blds = &Bls[sq * 72 + (seg << 3)];

  for (int kt = 0; kt < nkt; ++kt) {
    const int k0 = kt << 5;
    *reinterpret_cast<bf16x8*>(alds) =
        *reinterpret_cast<const bf16x8*>(arow + k0 + (seg << 3));
    *reinterpret_cast<bf16x8*>(blds) =
        *reinterpret_cast<const bf16x8*>(brow + k0 + (seg << 3));
    __syncthreads();

    bf16x8 af[2], bfr[2];
#pragma unroll
    for (int mq = 0; mq < 2; ++mq)
      af[mq] = *reinterpret_cast<const bf16x8*>(
          &Als[(wq * 32 + mq * 16 + lm) * 72 + lk]);
#pragma unroll
    for (int nv = 0; nv < 2; ++nv)
      bfr[nv] = *reinterpret_cast<const bf16x8*>(
          &Bls[(wv * 32 + nv * 16 + lm) * 72 + lk]);
#pragma unroll
    for (int mq = 0; mq < 2; ++mq)
#pragma unroll
      for (int nv = 0; nv < 2; ++nv)
        acc[mq][nv] = __builtin_amdgcn_mfma_f32_16x16x32_bf16(
            af[mq], bfr[nv], acc[mq][nv], 0, 0, 0);
    __syncthreads();
  }

  // epilogue: D lane mapping col=lane&15, row=(lane>>4)*4+j  [m89-verified]
  const int rbase = (l >> 4) << 2;
#pragma unroll
  for (int mq = 0; mq < 2; ++mq) {
#pragma unroll
    for (int nv = 0; nv < 2; ++nv) {
      const int qg = q0 + wq * 32 + mq * 16 + rbase;
      const int vg = v0 + wv * 32 + nv * 16 + lm;
#pragma unroll
      for (int j = 0; j < 4; ++j)
        out[((size_t)(b * NQ + qg + j)) * DV + vg] = acc[mq][nv][j];
    }
  }
}

extern "C" void kernel_launch(void* const* d_in, const int* in_sizes, int n_in,
                              void* d_out, int out_size, void* d_ws, size_t ws_size,
                              hipStream_t stream) {
  (void)in_sizes; (void)n_in; (void)out_size; (void)ws_size;
  const float* queries = (const float*)d_in[0];
  const float* keys    = (const float*)d_in[1];
  const float* values  = (const float*)d_in[2];
  const float* Wq      = (const float*)d_in[3];
  const float* Wk      = (const float*)d_in[4];
  const float* Wv      = (const float*)d_in[5];
  const int*   vlens   = (const int*)d_in[6];
  float* out = (float*)d_out;
  float* ws = (float*)d_ws;

  // ws floats (NON-OVERLAPPING):
  //   eq       [0,        262144)
  //   ekT4     [262144,   524288)
  //   attnQ    [524288,  1048576)  (1,048,576 ushort = 524,288 f-slots)
  //   Vt       [1048576, 1572864)  (1,048,576 ushort = 524,288 f-slots)
  //   projpart [1572864, 5767168)
  float* eq   = ws;
  float* ekT4 = ws + 262144;
  unsigned short* attnQ = (unsigned short*)(ws + 524288);
  unsigned short* Vt    = (unsigned short*)(ws + 1048576);
  float* projpart = ws + 1572864;

  proj_gemm_kernel<<<512, 256, 0, stream>>>(queries, keys, Wq, Wk, vlens, projpart);
  combo_kernel<<<768, 256, 0, stream>>>(projpart, values, vlens, eq, ekT4, Vt);
  scores_softmax_kernel<<<512, 1024, 0, stream>>>(eq, ekT4, Wv, vlens, attnQ);
  pv_mfma_kernel<<<256, 256, 0, stream>>>(attnQ, Vt, vlens, out);
}